// Round 15
// baseline (999.130 us; speedup 1.0000x reference)
//
#include <hip/hip_runtime.h>
#include <math.h>

namespace {

constexpr int BATCH = 2;
constexpr int H = 1080;
constexpr int W = 1920;
constexpr int HW = H * W;
constexpr int PL = BATCH * HW;          // elements per channel-plane (all batches)
constexpr int NTH = 256;

// ---------------- conv tile geometry ----------------
// 256x8 outputs per 256-thread block, 8 px per thread along x.
// LDS halo tile 258x10, row stride padded to 260 (tx*8 float4s 32B-aligned).
constexpr int BX = 256;
constexpr int BY = 8;
constexpr int LW = 260;
constexpr int LH = 10;
constexpr int LDSN = LW * LH;           // 2600 floats = 10.4 KB
constexpr int NSTG = (LDSN + NTH - 1) / NTH;   // 11 staging slots/thread

// ---------------- fused box geometry ----------------
constexpr int RMAX = 6;                 // largest radius (K=13)
constexpr int SW_B = 240;               // output columns per block strip
constexpr int COLS = SW_B + 2 * RMAX;   // 252 owned columns (incl. halo)
constexpr int SH_B = 4;                 // measured 191us

__device__ __forceinline__ float gamma22(float v) {
    return v > 0.f ? exp2f(0.45454545454545453f * log2f(v)) : 0.f;
}

// Fused 3x3 conv, 8 outputs/thread. SAME proven structure as the R5 4px
// kernel (single static tile, direct name access, 2 barriers/channel,
// aligned float4 LDS reads) -- only the tile GEOMETRY scales (the one
// category of conv change that has ever helped, R2->R3). RULE (3 failures):
// do not add indirection over the tile base or restructure the barrier
// schedule; hipcc drops b128 vectorization -> 8-way conflicts.
template<int CIN, int COUT, bool GAMMA, bool RELU, bool HEAD>
__global__ __launch_bounds__(NTH) void conv8_k(
        const float* __restrict__ in, const float* __restrict__ wgt,
        const float* __restrict__ bias, float* __restrict__ out)
{
    __shared__ float tile[LDSN];

    const int tx = threadIdx.x & 31;    // 32 groups of 8 px in x
    const int ty = threadIdx.x >> 5;    // 8 rows
    const int x0 = blockIdx.x * BX;
    const int y0 = blockIdx.y * BY;
    const int b  = blockIdx.z;

    const bool sok = x0 + tx * 8 < W;   // partial last block in x (x0=1792)

    float acc[COUT][8];
#pragma unroll
    for (int co = 0; co < COUT; ++co) {
        float bv = bias[co];
#pragma unroll
        for (int p = 0; p < 8; ++p) acc[co][p] = bv;
    }

    float rg[NSTG];

    auto stage_load = [&](int ci) {
#pragma unroll
        for (int s = 0; s < NSTG; ++s) {
            int i = threadIdx.x + s * NTH;
            float v = 0.f;
            if (i < LDSN) {
                int r = i / LW, c = i - r * LW;
                int gy = y0 + r - 1, gx = x0 + c - 1;
                if (c < 258 && gy >= 0 && gy < H && gx >= 0 && gx < W) {
                    if (GAMMA) {
                        if (ci < 3) {
                            float a  = in[((size_t)b * 10 + ci) * HW + (size_t)gy * W + gx];
                            float al = in[((size_t)b * 10 + ci + 3) * HW + (size_t)gy * W + gx];
                            v = gamma22(a * al);
                        } else {
                            v = in[((size_t)b * 10 + ci) * HW + (size_t)gy * W + gx];
                        }
                    } else {
                        v = in[(size_t)ci * PL + (size_t)b * HW + (size_t)gy * W + gx];
                    }
                }
            }
            rg[s] = v;
        }
    };

    stage_load(0);

    for (int ci = 0; ci < CIN; ++ci) {
        __syncthreads();
#pragma unroll
        for (int s = 0; s < NSTG; ++s) {
            int i = threadIdx.x + s * NTH;
            if (i < LDSN) tile[i] = rg[s];
        }
        __syncthreads();

        if (ci + 1 < CIN) stage_load(ci + 1);   // hide loads under FMAs

        // 10-col window per row via THREE aligned float4 reads
        // (lane-contiguous b128 = conflict-free; tx*8 floats = 32B-aligned)
        float v[3][12];
#pragma unroll
        for (int ky = 0; ky < 3; ++ky) {
            int row = (ty + ky) * LW + tx * 8;
            float4 vA = *reinterpret_cast<const float4*>(&tile[row]);
            float4 vB = *reinterpret_cast<const float4*>(&tile[row + 4]);
            float4 vC = *reinterpret_cast<const float4*>(&tile[row + 8]);
            v[ky][0] = vA.x; v[ky][1]  = vA.y; v[ky][2]  = vA.z; v[ky][3]  = vA.w;
            v[ky][4] = vB.x; v[ky][5]  = vB.y; v[ky][6]  = vB.z; v[ky][7]  = vB.w;
            v[ky][8] = vC.x; v[ky][9]  = vC.y; v[ky][10] = vC.z; v[ky][11] = vC.w;
        }

#pragma unroll
        for (int ky = 0; ky < 3; ++ky) {
#pragma unroll
            for (int kx = 0; kx < 3; ++kx) {
#pragma unroll
                for (int co = 0; co < COUT; ++co) {
                    float w = wgt[(co * CIN + ci) * 9 + ky * 3 + kx];
#pragma unroll
                    for (int p = 0; p < 8; ++p)
                        acc[co][p] = fmaf(v[ky][p + kx], w, acc[co][p]);
                }
            }
        }
    }

    if (!sok) return;                    // partial block: nothing to store
    const int y = y0 + ty;
    const size_t obase = (size_t)b * HW + (size_t)y * W + x0 + tx * 8;

    if (HEAD) {
#pragma unroll
        for (int p = 0; p < 8; ++p) {
#pragma unroll
            for (int c = 0; c < 6; ++c)
                out[(size_t)c * PL + obase + p] = expf(acc[c][p]);
            float m = acc[6][p];
#pragma unroll
            for (int c = 7; c < 12; ++c) m = fmaxf(m, acc[c][p]);
            float e[6]; float s = 0.f;
#pragma unroll
            for (int c = 0; c < 6; ++c) { e[c] = expf(acc[6 + c][p] - m); s += e[c]; }
            float inv = 1.f / s;
#pragma unroll
            for (int c = 0; c < 6; ++c)
                out[(size_t)(6 + c) * PL + obase + p] = e[c] * inv;
        }
    } else {
#pragma unroll
        for (int co = 0; co < COUT; ++co) {
            float4 r0, r1;
            r0.x = RELU ? fmaxf(acc[co][0], 0.f) : acc[co][0];
            r0.y = RELU ? fmaxf(acc[co][1], 0.f) : acc[co][1];
            r0.z = RELU ? fmaxf(acc[co][2], 0.f) : acc[co][2];
            r0.w = RELU ? fmaxf(acc[co][3], 0.f) : acc[co][3];
            r1.x = RELU ? fmaxf(acc[co][4], 0.f) : acc[co][4];
            r1.y = RELU ? fmaxf(acc[co][5], 0.f) : acc[co][5];
            r1.z = RELU ? fmaxf(acc[co][6], 0.f) : acc[co][6];
            r1.w = RELU ? fmaxf(acc[co][7], 0.f) : acc[co][7];
            *reinterpret_cast<float4*>(&out[(size_t)co * PL + obase])     = r0;
            *reinterpret_cast<float4*>(&out[(size_t)co * PL + obase + 4]) = r1;
        }
    }
}

// All 6 guided-box scales fused (PROVEN R11 form + conditional priming).
// R12/R13 LESSON: single-wave variant failed nondeterministically; keep
// 4-wave blocks with real barriers.
__global__ __launch_bounds__(NTH) void box_all_k(
        const float* __restrict__ ga, const float* __restrict__ xin,
        float* __restrict__ outp)
{
    __shared__ float4 vls4[6 * NTH];    // [scale][column] -> 24 KB

    const int t  = threadIdx.x;
    const int x0 = blockIdx.x * SW_B;
    const int y0 = blockIdx.y * SH_B;
    const int b  = blockIdx.z;
    const int x  = x0 - RMAX + t;

    const bool tok = t < COLS;                    // owns a column slot
    const bool xok = tok && x >= 0 && x < W;      // column inside image
    const bool ook = t >= RMAX && t < RMAX + SW_B;

    const float* gb = ga + (size_t)b * HW;                 // + i*PL + y*W + x
    const float* xb = xin + (size_t)b * 10 * HW;           // + c*HW + y*W + x

    float vs[6][4];
#pragma unroll
    for (int i = 0; i < 6; ++i)
#pragma unroll
        for (int c = 0; c < 4; ++c) vs[i][c] = 0.f;

    // ---- prime vertical sums for output row y0 ----
    // g[i] loaded ONLY for |r| <= i+1 (guards fold at compile time):
    // 48 instead of 78 scattered g-loads per lane.
#pragma unroll
    for (int r = -RMAX; r <= RMAX; ++r) {
        int yy = y0 + r;
        const bool rowok = xok && yy >= 0 && yy < H;
        size_t ro = (size_t)yy * W + x;
        float ir0 = 0.f, ir1 = 0.f, ir2 = 0.f;
        if (rowok) {
            ir0 = xb[ro];
            ir1 = xb[(size_t)HW + ro];
            ir2 = xb[(size_t)2 * HW + ro];
        }
#pragma unroll
        for (int i = 0; i < 6; ++i) {
            if (r >= -(i + 1) && r <= (i + 1)) {   // compile-time folded
                float g = rowok ? gb[(size_t)i * PL + ro] : 0.f;
                vs[i][0] += g;
                vs[i][1] = fmaf(g, ir0, vs[i][1]);
                vs[i][2] = fmaf(g, ir1, vs[i][2]);
                vs[i][3] = fmaf(g, ir2, vs[i][3]);
            }
        }
    }

    // ---- main row loop ----
    for (int dy = 0; dy < SH_B; ++dy) {
        const int y = y0 + dy;
        const size_t ro = (size_t)y * W + x;

        // preload alpha/alb for this row before the barrier (overlaps wait)
        float al[6], ab[3];
        if (ook) {
#pragma unroll
            for (int i = 0; i < 6; ++i) al[i] = gb[(size_t)(6 + i) * PL + ro];
#pragma unroll
            for (int c = 0; c < 3; ++c) ab[c] = xb[(size_t)(3 + c) * HW + ro];
        }

        if (tok) {
#pragma unroll
            for (int i = 0; i < 6; ++i)
                vls4[i * NTH + t] = make_float4(vs[i][0], vs[i][1], vs[i][2], vs[i][3]);
        }
        __syncthreads();

        // ---- slide vs to row y+1 now: vs is dead until next LDS write,
        // so these loads fly while the h-pass below computes ----
        if (dy + 1 < SH_B && xok) {
#pragma unroll
            for (int i = 0; i < 6; ++i) {
                const int R = i + 1;
                int ya = y + 1 + R;            // entering row
                int yr = y - R;                // leaving row
                if (ya < H) {
                    size_t r2 = (size_t)ya * W + x;
                    float g = gb[(size_t)i * PL + r2];
                    vs[i][0] += g;
                    vs[i][1] = fmaf(g, xb[r2], vs[i][1]);
                    vs[i][2] = fmaf(g, xb[(size_t)HW + r2], vs[i][2]);
                    vs[i][3] = fmaf(g, xb[(size_t)2 * HW + r2], vs[i][3]);
                }
                if (yr >= 0) {
                    size_t r2 = (size_t)yr * W + x;
                    float g = gb[(size_t)i * PL + r2];
                    vs[i][0] -= g;
                    vs[i][1] = fmaf(-g, xb[r2], vs[i][1]);
                    vs[i][2] = fmaf(-g, xb[(size_t)HW + r2], vs[i][2]);
                    vs[i][3] = fmaf(-g, xb[(size_t)2 * HW + r2], vs[i][3]);
                }
            }
        }

        if (ook) {
            float o0 = 0.f, o1 = 0.f, o2 = 0.f;
#pragma unroll
            for (int i = 0; i < 6; ++i) {
                const int R = i + 1;
                float sw = 0.f, s0 = 0.f, s1 = 0.f, s2 = 0.f;
#pragma unroll
                for (int dx = -R; dx <= R; ++dx) {
                    float4 v = vls4[i * NTH + t + dx];
                    sw += v.x; s0 += v.y; s1 += v.z; s2 += v.w;
                }
                float rw = al[i] / sw;
                o0 = fmaf(s0, rw, o0);
                o1 = fmaf(s1, rw, o1);
                o2 = fmaf(s2, rw, o2);
            }
            size_t o = (size_t)b * 3 * HW + ro;
            outp[o]                  = o0 * ab[0];
            outp[o + HW]             = o1 * ab[1];
            outp[o + (size_t)2 * HW] = o2 * ab[2];
        }
        __syncthreads();    // h-pass LDS reads done before next row's writes
    }
}

} // namespace

extern "C" void kernel_launch(void* const* d_in, const int* in_sizes, int n_in,
                              void* d_out, int out_size, void* d_ws, size_t ws_size,
                              hipStream_t stream)
{
    const float* xin = (const float*)d_in[0];
    const float* W1p = (const float*)d_in[1];
    const float* b1p = (const float*)d_in[2];
    const float* W2p = (const float*)d_in[3];
    const float* b2p = (const float*)d_in[4];
    const float* W3p = (const float*)d_in[5];
    const float* b3p = (const float*)d_in[6];
    float* outp = (float*)d_out;
    float* ws = (float*)d_ws;

    // ws layout (28 planes of PL floats):
    //   h1 : planes  0..13 ; h2 : planes 14..27 ; ga : planes 0..11 (reuses h1)
    float* h1 = ws;
    float* h2 = ws + (size_t)14 * PL;
    float* ga = ws;

    dim3 blk(NTH);
    dim3 cgrid((W + BX - 1) / BX, H / BY, BATCH);
    dim3 bgrid(W / SW_B, H / SH_B, BATCH);

    conv8_k<10, 14, true,  true,  false><<<cgrid, blk, 0, stream>>>(xin, W1p, b1p, h1);
    conv8_k<14, 14, false, true,  false><<<cgrid, blk, 0, stream>>>(h1,  W2p, b2p, h2);
    conv8_k<14, 12, false, false, true ><<<cgrid, blk, 0, stream>>>(h2,  W3p, b3p, ga);

    box_all_k<<<bgrid, blk, 0, stream>>>(ga, xin, outp);
}

// Round 16
// 660.118 us; speedup vs baseline: 1.5136x; 1.5136x over previous
//
#include <hip/hip_runtime.h>
#include <math.h>

namespace {

constexpr int BATCH = 2;
constexpr int H = 1080;
constexpr int W = 1920;
constexpr int HW = H * W;
constexpr int PL = BATCH * HW;          // elements per channel-plane (all batches)
constexpr int NTH = 256;

// ---------------- conv tile geometry ----------------
// 128x8 outputs per 256-thread block, 4 px per thread along x.
// LDS halo tile 130x10, row stride padded to 132 (16B-aligned float4 reads).
constexpr int BX = 128;
constexpr int BY = 8;
constexpr int LW = 132;
constexpr int LH = 10;
constexpr int LDSN = LW * LH;           // 1320 floats
constexpr int NSTG = (LDSN + NTH - 1) / NTH;   // 6 staging slots/thread

// ---------------- fused box geometry ----------------
constexpr int RMAX = 6;                 // largest radius (K=13)
constexpr int SW_B = 240;               // output columns per block strip
constexpr int COLS = SW_B + 2 * RMAX;   // 252 owned columns (incl. halo)
constexpr int SH_B = 4;                 // measured 191us (R14)

__device__ __forceinline__ float gamma22(float v) {
    return v > 0.f ? exp2f(0.45454545454545453f * log2f(v)) : 0.f;
}

// Fused 3x3 conv, 4 outputs/thread. FROZEN R5 structure (measured ~156us,
// ~0 LDS conflicts; reproduced 5x). CLOSED LINES, each with a measured
// regression: R6 runtime-indexed LDS base (238us), R8 array-ref param
// (491us), R10 pair-region at literal offset (216us), R15 8px/thread
// (420us: tx*8 -> 32B lane stride breaks lane-contiguity -> 1.9e7
// conflicts; VGPR 136 -> 10.9% occupancy). The conflict-free form needs
// 16B-PER-LANE CONTIGUOUS coverage (tx*4), single static tile, direct
// name access, 2 barriers/channel. Do not restructure.
template<int CIN, int COUT, bool GAMMA, bool RELU, bool HEAD>
__global__ __launch_bounds__(NTH) void conv4_k(
        const float* __restrict__ in, const float* __restrict__ wgt,
        const float* __restrict__ bias, float* __restrict__ out)
{
    __shared__ float tile[LDSN];

    const int tx = threadIdx.x & 31;
    const int ty = threadIdx.x >> 5;
    const int x0 = blockIdx.x * BX;
    const int y0 = blockIdx.y * BY;
    const int b  = blockIdx.z;

    float acc[COUT][4];
#pragma unroll
    for (int co = 0; co < COUT; ++co) {
        float bv = bias[co];
#pragma unroll
        for (int p = 0; p < 4; ++p) acc[co][p] = bv;
    }

    float rg[NSTG];

    auto stage_load = [&](int ci) {
#pragma unroll
        for (int s = 0; s < NSTG; ++s) {
            int i = threadIdx.x + s * NTH;
            float v = 0.f;
            if (i < LDSN) {
                int r = i / LW, c = i - r * LW;
                int gy = y0 + r - 1, gx = x0 + c - 1;
                if (c < 130 && gy >= 0 && gy < H && gx >= 0 && gx < W) {
                    if (GAMMA) {
                        if (ci < 3) {
                            float a  = in[((size_t)b * 10 + ci) * HW + (size_t)gy * W + gx];
                            float al = in[((size_t)b * 10 + ci + 3) * HW + (size_t)gy * W + gx];
                            v = gamma22(a * al);
                        } else {
                            v = in[((size_t)b * 10 + ci) * HW + (size_t)gy * W + gx];
                        }
                    } else {
                        v = in[(size_t)ci * PL + (size_t)b * HW + (size_t)gy * W + gx];
                    }
                }
            }
            rg[s] = v;
        }
    };

    stage_load(0);

    for (int ci = 0; ci < CIN; ++ci) {
        __syncthreads();
#pragma unroll
        for (int s = 0; s < NSTG; ++s) {
            int i = threadIdx.x + s * NTH;
            if (i < LDSN) tile[i] = rg[s];
        }
        __syncthreads();

        if (ci + 1 < CIN) stage_load(ci + 1);   // hide loads under FMAs

        // 6-col window per row via TWO aligned float4 reads (lane-contiguous
        // b128 = conflict-free LDS pattern); tile addressed by static name
        float v[3][6];
#pragma unroll
        for (int ky = 0; ky < 3; ++ky) {
            int row = (ty + ky) * LW + tx * 4;
            float4 vA = *reinterpret_cast<const float4*>(&tile[row]);
            float4 vB = *reinterpret_cast<const float4*>(&tile[row + 4]);
            v[ky][0] = vA.x; v[ky][1] = vA.y; v[ky][2] = vA.z; v[ky][3] = vA.w;
            v[ky][4] = vB.x; v[ky][5] = vB.y;
        }

#pragma unroll
        for (int ky = 0; ky < 3; ++ky) {
#pragma unroll
            for (int kx = 0; kx < 3; ++kx) {
#pragma unroll
                for (int co = 0; co < COUT; ++co) {
                    float w = wgt[(co * CIN + ci) * 9 + ky * 3 + kx];
#pragma unroll
                    for (int p = 0; p < 4; ++p)
                        acc[co][p] = fmaf(v[ky][p + kx], w, acc[co][p]);
                }
            }
        }
    }

    const int y = y0 + ty;
    const size_t obase = (size_t)b * HW + (size_t)y * W + x0 + tx * 4;

    if (HEAD) {
#pragma unroll
        for (int p = 0; p < 4; ++p) {
#pragma unroll
            for (int c = 0; c < 6; ++c)
                out[(size_t)c * PL + obase + p] = expf(acc[c][p]);
            float m = acc[6][p];
#pragma unroll
            for (int c = 7; c < 12; ++c) m = fmaxf(m, acc[c][p]);
            float e[6]; float s = 0.f;
#pragma unroll
            for (int c = 0; c < 6; ++c) { e[c] = expf(acc[6 + c][p] - m); s += e[c]; }
            float inv = 1.f / s;
#pragma unroll
            for (int c = 0; c < 6; ++c)
                out[(size_t)(6 + c) * PL + obase + p] = e[c] * inv;
        }
    } else {
#pragma unroll
        for (int co = 0; co < COUT; ++co) {
            float4 r;
            r.x = RELU ? fmaxf(acc[co][0], 0.f) : acc[co][0];
            r.y = RELU ? fmaxf(acc[co][1], 0.f) : acc[co][1];
            r.z = RELU ? fmaxf(acc[co][2], 0.f) : acc[co][2];
            r.w = RELU ? fmaxf(acc[co][3], 0.f) : acc[co][3];
            *reinterpret_cast<float4*>(&out[(size_t)co * PL + obase]) = r;
        }
    }
}

// All 6 guided-box scales fused (R11 form + R15 conditional priming).
// R12/R13 LESSON: single-wave variant failed nondeterministically; keep
// 4-wave blocks with real barriers.
__global__ __launch_bounds__(NTH) void box_all_k(
        const float* __restrict__ ga, const float* __restrict__ xin,
        float* __restrict__ outp)
{
    __shared__ float4 vls4[6 * NTH];    // [scale][column] -> 24 KB

    const int t  = threadIdx.x;
    const int x0 = blockIdx.x * SW_B;
    const int y0 = blockIdx.y * SH_B;
    const int b  = blockIdx.z;
    const int x  = x0 - RMAX + t;

    const bool tok = t < COLS;                    // owns a column slot
    const bool xok = tok && x >= 0 && x < W;      // column inside image
    const bool ook = t >= RMAX && t < RMAX + SW_B;

    const float* gb = ga + (size_t)b * HW;                 // + i*PL + y*W + x
    const float* xb = xin + (size_t)b * 10 * HW;           // + c*HW + y*W + x

    float vs[6][4];
#pragma unroll
    for (int i = 0; i < 6; ++i)
#pragma unroll
        for (int c = 0; c < 4; ++c) vs[i][c] = 0.f;

    // ---- prime vertical sums for output row y0 ----
    // g[i] loaded ONLY for |r| <= i+1 (guards fold at compile time):
    // 48 instead of 78 scattered g-loads per lane.
#pragma unroll
    for (int r = -RMAX; r <= RMAX; ++r) {
        int yy = y0 + r;
        const bool rowok = xok && yy >= 0 && yy < H;
        size_t ro = (size_t)yy * W + x;
        float ir0 = 0.f, ir1 = 0.f, ir2 = 0.f;
        if (rowok) {
            ir0 = xb[ro];
            ir1 = xb[(size_t)HW + ro];
            ir2 = xb[(size_t)2 * HW + ro];
        }
#pragma unroll
        for (int i = 0; i < 6; ++i) {
            if (r >= -(i + 1) && r <= (i + 1)) {   // compile-time folded
                float g = rowok ? gb[(size_t)i * PL + ro] : 0.f;
                vs[i][0] += g;
                vs[i][1] = fmaf(g, ir0, vs[i][1]);
                vs[i][2] = fmaf(g, ir1, vs[i][2]);
                vs[i][3] = fmaf(g, ir2, vs[i][3]);
            }
        }
    }

    // ---- main row loop ----
    for (int dy = 0; dy < SH_B; ++dy) {
        const int y = y0 + dy;
        const size_t ro = (size_t)y * W + x;

        // preload alpha/alb for this row before the barrier (overlaps wait)
        float al[6], ab[3];
        if (ook) {
#pragma unroll
            for (int i = 0; i < 6; ++i) al[i] = gb[(size_t)(6 + i) * PL + ro];
#pragma unroll
            for (int c = 0; c < 3; ++c) ab[c] = xb[(size_t)(3 + c) * HW + ro];
        }

        if (tok) {
#pragma unroll
            for (int i = 0; i < 6; ++i)
                vls4[i * NTH + t] = make_float4(vs[i][0], vs[i][1], vs[i][2], vs[i][3]);
        }
        __syncthreads();

        // ---- slide vs to row y+1 now: vs is dead until next LDS write,
        // so these loads fly while the h-pass below computes ----
        if (dy + 1 < SH_B && xok) {
#pragma unroll
            for (int i = 0; i < 6; ++i) {
                const int R = i + 1;
                int ya = y + 1 + R;            // entering row
                int yr = y - R;                // leaving row
                if (ya < H) {
                    size_t r2 = (size_t)ya * W + x;
                    float g = gb[(size_t)i * PL + r2];
                    vs[i][0] += g;
                    vs[i][1] = fmaf(g, xb[r2], vs[i][1]);
                    vs[i][2] = fmaf(g, xb[(size_t)HW + r2], vs[i][2]);
                    vs[i][3] = fmaf(g, xb[(size_t)2 * HW + r2], vs[i][3]);
                }
                if (yr >= 0) {
                    size_t r2 = (size_t)yr * W + x;
                    float g = gb[(size_t)i * PL + r2];
                    vs[i][0] -= g;
                    vs[i][1] = fmaf(-g, xb[r2], vs[i][1]);
                    vs[i][2] = fmaf(-g, xb[(size_t)HW + r2], vs[i][2]);
                    vs[i][3] = fmaf(-g, xb[(size_t)2 * HW + r2], vs[i][3]);
                }
            }
        }

        if (ook) {
            float o0 = 0.f, o1 = 0.f, o2 = 0.f;
#pragma unroll
            for (int i = 0; i < 6; ++i) {
                const int R = i + 1;
                float sw = 0.f, s0 = 0.f, s1 = 0.f, s2 = 0.f;
#pragma unroll
                for (int dx = -R; dx <= R; ++dx) {
                    float4 v = vls4[i * NTH + t + dx];
                    sw += v.x; s0 += v.y; s1 += v.z; s2 += v.w;
                }
                float rw = al[i] / sw;
                o0 = fmaf(s0, rw, o0);
                o1 = fmaf(s1, rw, o1);
                o2 = fmaf(s2, rw, o2);
            }
            size_t o = (size_t)b * 3 * HW + ro;
            outp[o]                  = o0 * ab[0];
            outp[o + HW]             = o1 * ab[1];
            outp[o + (size_t)2 * HW] = o2 * ab[2];
        }
        __syncthreads();    // h-pass LDS reads done before next row's writes
    }
}

} // namespace

extern "C" void kernel_launch(void* const* d_in, const int* in_sizes, int n_in,
                              void* d_out, int out_size, void* d_ws, size_t ws_size,
                              hipStream_t stream)
{
    const float* xin = (const float*)d_in[0];
    const float* W1p = (const float*)d_in[1];
    const float* b1p = (const float*)d_in[2];
    const float* W2p = (const float*)d_in[3];
    const float* b2p = (const float*)d_in[4];
    const float* W3p = (const float*)d_in[5];
    const float* b3p = (const float*)d_in[6];
    float* outp = (float*)d_out;
    float* ws = (float*)d_ws;

    // ws layout (28 planes of PL floats):
    //   h1 : planes  0..13 ; h2 : planes 14..27 ; ga : planes 0..11 (reuses h1)
    float* h1 = ws;
    float* h2 = ws + (size_t)14 * PL;
    float* ga = ws;

    dim3 blk(NTH);
    dim3 cgrid(W / BX, H / BY, BATCH);
    dim3 bgrid(W / SW_B, H / SH_B, BATCH);

    conv4_k<10, 14, true,  true,  false><<<cgrid, blk, 0, stream>>>(xin, W1p, b1p, h1);
    conv4_k<14, 14, false, true,  false><<<cgrid, blk, 0, stream>>>(h1,  W2p, b2p, h2);
    conv4_k<14, 12, false, false, true ><<<cgrid, blk, 0, stream>>>(h2,  W3p, b3p, ga);

    box_all_k<<<bgrid, blk, 0, stream>>>(ga, xin, outp);
}